// Round 6
// baseline (20.626 us; speedup 1.0000x reference)
//
#include <hip/hip_runtime.h>

typedef short short8 __attribute__((ext_vector_type(8)));
typedef float f32x4  __attribute__((ext_vector_type(4)));

#define IN_F 4096
#define OUT_F 11008
#define GROUPSIZE 128
#define NGROUPS 32
#define QROWS 512
#define ZCOLS 1376
#define KSPL 8                        // K-split: 4 groups (512 K) per split
#define WS_BYTES ((size_t)KSPL * 4 * OUT_F * sizeof(float))   // 1.4 MB

__device__ __forceinline__ unsigned cvt_pk_bf16(float a, float b) {
    unsigned r;
    asm("v_cvt_pk_bf16_f32 %0, %1, %2" : "=v"(r) : "v"(a), "v"(b));
    return r;   // {lo16: bf16(a), hi16: bf16(b)}
}

// ============ Stage 1: MFMA dequant-GEMM, grid (OUT_F/64, KSPL) =============
// Block 256 = 4 waves. Wave: 16 cols x 4 groups (512 K). Lane: col = lane&15,
// k-block kb = lane>>4. One packed int32 unpacked per lane per K-tile feeds
// the B-frag directly (8 consecutive K per col = GPTQ packing = frag layout).
__global__ __launch_bounds__(256) void gptq_s1_mfma(
    const float* __restrict__ x,       // [4, IN_F]
    const float* __restrict__ scales,  // [NGROUPS, OUT_F]
    const int*   __restrict__ qweight, // [QROWS, OUT_F]
    const int*   __restrict__ qzeros,  // [NGROUPS, ZCOLS]
    float*       __restrict__ ws)      // [KSPL, 4, OUT_F]
{
    const int tid  = threadIdx.x;
    const int lane = tid & 63;
    const int wv   = tid >> 6;          // wave 0..3
    const int ks   = blockIdx.y;        // K-split 0..7
    const int ncol = lane & 15;
    const int kb   = lane >> 4;         // 0..3
    const int col  = blockIdx.x * 64 + wv * 16 + ncol;

    float tot[4] = {0.f, 0.f, 0.f, 0.f};

    #pragma unroll
    for (int gi = 0; gi < 4; ++gi) {
        const int g = ks * 4 + gi;
        const unsigned qz = (unsigned)qzeros[g * ZCOLS + (col >> 3)];
        const float z  = (float)(((qz >> (4u * (unsigned)(col & 7))) & 0xFu) + 1u);
        const float sc = scales[g * OUT_F + col];

        f32x4 acc = {0.f, 0.f, 0.f, 0.f};
        #pragma unroll
        for (int kt = 0; kt < 4; ++kt) {
            const int k0  = g * GROUPSIZE + kt * 32;
            const int row = (k0 >> 3) + kb;                 // packed qweight row
            const unsigned w = (unsigned)qweight[row * OUT_F + col];

            // B-frag: (q - z), exact small integers in bf16
            const unsigned lo = w & 0x0F0F0F0Fu;            // nibbles 0,2,4,6
            const unsigned hi = (w >> 4) & 0x0F0F0F0Fu;     // nibbles 1,3,5,7
            union { unsigned u[4]; short8 s; } bf;
            bf.u[0] = cvt_pk_bf16((float)(lo & 0xFFu) - z,         (float)(hi & 0xFFu) - z);
            bf.u[1] = cvt_pk_bf16((float)((lo >> 8) & 0xFFu) - z,  (float)((hi >> 8) & 0xFFu) - z);
            bf.u[2] = cvt_pk_bf16((float)((lo >> 16) & 0xFFu) - z, (float)((hi >> 16) & 0xFFu) - z);
            bf.u[3] = cvt_pk_bf16((float)(lo >> 24) - z,           (float)(hi >> 24) - z);

            // A-frag: x rows 0..3 (tokens), rows 4..15 zero-padded
            union { unsigned u[4]; short8 s; } af;
            af.u[0] = 0u; af.u[1] = 0u; af.u[2] = 0u; af.u[3] = 0u;
            if (ncol < 4) {
                const float* xp = x + ncol * IN_F + k0 + kb * 8;
                const float4 xa = *(const float4*)xp;
                const float4 xb = *(const float4*)(xp + 4);
                af.u[0] = cvt_pk_bf16(xa.x, xa.y);
                af.u[1] = cvt_pk_bf16(xa.z, xa.w);
                af.u[2] = cvt_pk_bf16(xb.x, xb.y);
                af.u[3] = cvt_pk_bf16(xb.z, xb.w);
            }

            acc = __builtin_amdgcn_mfma_f32_16x16x32_bf16(af.s, bf.s, acc, 0, 0, 0);
        }
        #pragma unroll
        for (int r = 0; r < 4; ++r) tot[r] += sc * acc[r];
    }

    // C/D mapping: col = lane&15, row = (lane>>4)*4 + r. Tokens are rows 0..3,
    // held by lanes 0..15 in regs 0..3. Rows 4..15 (lanes 16+) are zeros.
    if (lane < 16) {
        #pragma unroll
        for (int r = 0; r < 4; ++r)
            ws[(size_t)(ks * 4 + r) * OUT_F + col] = tot[r];
    }
}

// ============ Stage 2: reduce KSPL partials + bias (proven) ============
__global__ __launch_bounds__(256) void gptq_reduce_kernel(
    const float* __restrict__ ws,      // [KSPL, 4, OUT_F]
    const float* __restrict__ bias,
    float*       __restrict__ out)     // [4, OUT_F]
{
    const int n = blockIdx.x * 256 + threadIdx.x;   // 11008 = 43*256
    const int m = blockIdx.y;
    float s0 = bias[n], s1 = 0.f;
    #pragma unroll
    for (int ks = 0; ks < KSPL; ks += 2) {
        s0 += ws[(size_t)((ks + 0) * 4 + m) * OUT_F + n];
        s1 += ws[(size_t)((ks + 1) * 4 + m) * OUT_F + n];
    }
    out[m * OUT_F + n] = s0 + s1;
}

// ============ Fallback: fused single kernel (no ws) ============
__global__ __launch_bounds__(256) void gptq_gemv_fused(
    const float* __restrict__ x, const float* __restrict__ scales,
    const float* __restrict__ bias, const int* __restrict__ qweight,
    const int* __restrict__ qzeros, float* __restrict__ out)
{
    __shared__ float part[4][4][64];
    const int tid = threadIdx.x;
    const int col = tid & 63;
    const int kp  = tid >> 6;
    const int n   = blockIdx.x * 64 + col;
    const unsigned zshift = 4u * (unsigned)(n & 7);
    const int zcol = n >> 3;
    float acc[4] = {0.f, 0.f, 0.f, 0.f};
    for (int g = kp * 8; g < kp * 8 + 8; ++g) {
        const unsigned qz = (unsigned)qzeros[g * ZCOLS + zcol];
        const float zf = (float)(((qz >> zshift) & 0xFu) + 1u);
        const float sc = scales[g * OUT_F + n];
        float ga[4] = {0.f, 0.f, 0.f, 0.f};
        #pragma unroll 4
        for (int t = 0; t < 16; ++t) {
            const int kk = g * 16 + t;
            const unsigned w = (unsigned)qweight[kk * OUT_F + n];
            const unsigned lo = w & 0x0F0F0F0Fu;
            const unsigned hi = (w >> 4) & 0x0F0F0F0Fu;
            float q[8];
            q[0] = (float)(lo & 0xFFu);         q[1] = (float)(hi & 0xFFu);
            q[2] = (float)((lo >> 8) & 0xFFu);  q[3] = (float)((hi >> 8) & 0xFFu);
            q[4] = (float)((lo >> 16) & 0xFFu); q[5] = (float)((hi >> 16) & 0xFFu);
            q[6] = (float)(lo >> 24);           q[7] = (float)(hi >> 24);
            const int k0 = kk * 8;
            #pragma unroll
            for (int j = 0; j < 8; ++j) {
                const float d = q[j] - zf;
                #pragma unroll
                for (int m = 0; m < 4; ++m) ga[m] += x[m * IN_F + k0 + j] * d;
            }
        }
        #pragma unroll
        for (int m = 0; m < 4; ++m) acc[m] += sc * ga[m];
    }
    #pragma unroll
    for (int m = 0; m < 4; ++m) part[kp][m][col] = acc[m];
    __syncthreads();
    const int m = tid >> 6;
    const int c = tid & 63;
    const int nn = blockIdx.x * 64 + c;
    const float s = part[0][m][c] + part[1][m][c] + part[2][m][c] + part[3][m][c];
    out[m * OUT_F + nn] = s + bias[nn];
}

extern "C" void kernel_launch(void* const* d_in, const int* in_sizes, int n_in,
                              void* d_out, int out_size, void* d_ws, size_t ws_size,
                              hipStream_t stream) {
    const float* x       = (const float*)d_in[0];
    const float* scales  = (const float*)d_in[1];
    const float* bias    = (const float*)d_in[2];
    const int*   qweight = (const int*)d_in[3];
    const int*   qzeros  = (const int*)d_in[4];
    float*       out     = (float*)d_out;

    if (ws_size >= WS_BYTES) {
        float* ws = (float*)d_ws;
        dim3 g1(OUT_F / 64, KSPL);    // (172, 8) = 1376 blocks
        gptq_s1_mfma<<<g1, 256, 0, stream>>>(x, scales, qweight, qzeros, ws);
        dim3 g2(OUT_F / 256, 4);      // (43, 4)
        gptq_reduce_kernel<<<g2, 256, 0, stream>>>(ws, bias, out);
    } else {
        dim3 grid(OUT_F / 64);
        gptq_gemv_fused<<<grid, 256, 0, stream>>>(x, scales, bias, qweight, qzeros, out);
    }
}